// Round 2
// baseline (195.687 us; speedup 1.0000x reference)
//
#include <hip/hip_runtime.h>
#include <math.h>

#define AB 128   // A == B == 128
#define NN 64    // N
#define HD 1024  // H

// fp32 -> f16 hi/lo split scales. Z ~ N(0,1) -> x256 keeps lo normal;
// F entries ~1e-2 -> x64. out = acc * gamma * 2^-20.
#define SFZ 256.0f
#define SFF 64.0f
#define DESCALE (1.0f / 1048576.0f)  // 2^-(8+6+6)

typedef _Float16 half8 __attribute__((ext_vector_type(8)));
typedef float f32x4 __attribute__((ext_vector_type(4)));
typedef unsigned u32x4 __attribute__((ext_vector_type(4)));

// ---------------------------------------------------------------------------
// ws layout (halves):
//   [0,     8192)   FXhi[m][b]   row-major, scaled by 64
//   [8192,  16384)  FXlo[m][b]
//   [16384, 24576)  FYhi[n][a]
//   [24576, 32768)  FYlo[n][a]
//   float at half-offset 32768 (byte 65536): gamma * 2^-20
// ---------------------------------------------------------------------------

__device__ __forceinline__ float wave_reduce(float v) {
  v += __shfl_down(v, 32);
  v += __shfl_down(v, 16);
  v += __shfl_down(v, 8);
  v += __shfl_down(v, 4);
  v += __shfl_down(v, 2);
  v += __shfl_down(v, 1);
  return v;  // valid in lane 0
}

__global__ __launch_bounds__(1024) void fb_setup(
    const float* __restrict__ h, const float* __restrict__ Ww,
    const float* __restrict__ Wb, void* __restrict__ wsv) {
  __shared__ float redp[16][5];
  __shared__ float reds[16][2];
  __shared__ float sc[5];
  __shared__ float ssum[2];
  const int tid = threadIdx.x;
  const int lane = tid & 63;
  const int wv = tid >> 6;

  const float hv = h[tid];
  float p[5];
#pragma unroll
  for (int j = 0; j < 5; ++j) p[j] = hv * Ww[j * HD + tid];
#pragma unroll
  for (int j = 0; j < 5; ++j) {
    float r = wave_reduce(p[j]);
    if (lane == 0) redp[wv][j] = r;
  }
  __syncthreads();
  if (tid < 5) {
    float s = Wb[tid];
#pragma unroll
    for (int w = 0; w < 16; ++w) s += redp[w][tid];
    sc[tid] = s;
  }
  __syncthreads();

  const float gt_X = sc[0], gt_Y = sc[1], log_var = sc[2], log_dt = sc[3];
  const float var = expf(log_var + 1e-8f);
  const float g_X = (129.0f * (gt_X + 1.0f)) / 2.0f;
  const float g_Y = (129.0f * (gt_Y + 1.0f)) / 2.0f;
  const float d = (expf(log_dt) * 127.0f) / 63.0f;
  const float twovar = 2.0f * var;

  float fyv[8], fxv[8];
  float sY = 0.f, sX = 0.f;
#pragma unroll
  for (int c = 0; c < 8; ++c) {
    const int idx = tid + 1024 * c;
    const int n = idx >> 7;
    const int col = idx & 127;
    const float idxn = (float)n - 32.5f;
    const float muX = g_X + idxn * d;
    const float muY = g_Y + idxn * d;
    const float dx = (float)col - muX;
    const float dy = (float)col - muY;
    const float fx = expf(-(dx * dx) / twovar);
    const float fy = expf(-(dy * dy) / twovar);
    fyv[c] = fy;
    fxv[c] = fx;
    sY += fy;
    sX += fx;
  }
  {
    float rY = wave_reduce(sY);
    float rX = wave_reduce(sX);
    if (lane == 0) { reds[wv][0] = rY; reds[wv][1] = rX; }
  }
  __syncthreads();
  if (tid < 2) {
    float s = 0.f;
#pragma unroll
    for (int w = 0; w < 16; ++w) s += reds[w][tid];
    ssum[tid] = s;
  }
  __syncthreads();
  const float invY = 1.0f / ssum[0];
  const float invX = 1.0f / ssum[1];

  _Float16* FXhi = (_Float16*)wsv;
  _Float16* FXlo = FXhi + NN * AB;
  _Float16* FYhi = FXhi + 2 * NN * AB;
  _Float16* FYlo = FXhi + 3 * NN * AB;

#pragma unroll
  for (int c = 0; c < 8; ++c) {
    const int idx = tid + 1024 * c;  // == n*128 + col, row-major
    const float vy = fyv[c] * invY * SFF;
    const float vx = fxv[c] * invX * SFF;
    const _Float16 yh = (_Float16)vy;
    const _Float16 xh2 = (_Float16)vx;
    FYhi[idx] = yh;
    FYlo[idx] = (_Float16)(vy - (float)yh);
    FXhi[idx] = xh2;
    FXlo[idx] = (_Float16)(vx - (float)xh2);
  }
  if (tid == 0) ((float*)wsv)[2 * NN * AB] = expf(sc[4]) * DESCALE;
}

// ---------------------------------------------------------------------------
// fb_filt: one block (256 thr = 4 waves) per image.
// Stage 1: S'(64x128) = FXs @ Zs^T, Z B-frags loaded straight from global
//   (8 consecutive fp32/lane), 1-ks-ahead double-buffered prefetch so the
//   next tile's 4 dwordx4 are in flight while current splits/MFMAs run
//   (counted-vmcnt pipeline).
// S' -> LDS packed (hi16|lo16) u32, [64][128] with XOR unit-swizzle
//   col ^ ((row&7)<<2): 32 KB exact, both write (b32) and read (b128)
//   patterns stay at the free 2-way level.
// Stage 2: out = FYs @ S'^T, DS reads prefetched 1 mt ahead; D layout
//   gives dword stores covering 64B lines in out[n][m] order.
// 3-product f16 emulation: Ahi*Bhi + Ahi*Blo + Alo*Bhi (fp32 acc).
// ---------------------------------------------------------------------------
__device__ __forceinline__ void split8(const f32x4 z0, const f32x4 z1,
                                       float s, half8& hi, half8& lo) {
#pragma unroll
  for (int e = 0; e < 8; ++e) {
    const float q = (e < 4 ? z0[e] : z1[e - 4]) * s;
    const _Float16 hh = (_Float16)q;
    hi[e] = hh;
    lo[e] = (_Float16)(q - (float)hh);
  }
}

__global__ __launch_bounds__(256, 4) void fb_filt(
    const float* __restrict__ x, const float* __restrict__ xh,
    const void* __restrict__ wsv, float* __restrict__ out) {
  __shared__ __align__(16) unsigned S_lds[NN * 128];  // 32768 B exact

  const int tid = threadIdx.x;
  const int lane = tid & 63;
  const int wv = tid >> 6;   // 0..3
  const int l15 = lane & 15;
  const int h4 = lane >> 4;  // 0..3
  const int bid = blockIdx.x;
  const int img = bid >> 1;
  const int which = bid & 1;
  const float* __restrict__ Z = (which ? xh : x) + (size_t)img * (AB * AB);
  const _Float16* __restrict__ FXhi = (const _Float16*)wsv;
  const _Float16* __restrict__ FXlo = FXhi + NN * AB;
  const _Float16* __restrict__ FYhi = FXhi + 2 * NN * AB;
  const _Float16* __restrict__ FYlo = FXhi + 3 * NN * AB;
  const float gamma_eff = ((const float*)wsv)[2 * NN * AB];  // s_load, early

  f32x4 acc[4][2];  // [m-tile][a-subtile within wave strip]
#pragma unroll
  for (int mt = 0; mt < 4; ++mt)
#pragma unroll
    for (int j = 0; j < 2; ++j) acc[mt][j] = {0.f, 0.f, 0.f, 0.f};

  // ---- Stage 1: double-buffered Z prefetch over ks ----
  const float* __restrict__ zrow = Z + (32 * wv + l15) * AB + 8 * h4;
  f32x4 zb[2][4];

#define ZLOAD(KS, BUF)                                            \
  do {                                                            \
    const float* p0_ = zrow + 32 * (KS);                          \
    const float* p1_ = zrow + 16 * AB + 32 * (KS);                \
    zb[BUF][0] = *(const f32x4*)p0_;                              \
    zb[BUF][1] = *(const f32x4*)(p0_ + 4);                        \
    zb[BUF][2] = *(const f32x4*)p1_;                              \
    zb[BUF][3] = *(const f32x4*)(p1_ + 4);                        \
  } while (0)

  ZLOAD(0, 0);
#pragma unroll
  for (int ks = 0; ks < 4; ++ks) {
    if (ks < 3) ZLOAD(ks + 1, (ks + 1) & 1);  // next tile in flight
    const int cur = ks & 1;
    half8 bhi[2], blo[2];
    split8(zb[cur][0], zb[cur][1], SFZ, bhi[0], blo[0]);
    split8(zb[cur][2], zb[cur][3], SFZ, bhi[1], blo[1]);
#pragma unroll
    for (int mt = 0; mt < 4; ++mt) {
      const int off = (16 * mt + l15) * AB + 32 * ks + 8 * h4;
      const half8 ahi = *(const half8*)(FXhi + off);
      const half8 alo = *(const half8*)(FXlo + off);
#pragma unroll
      for (int j = 0; j < 2; ++j) {
        acc[mt][j] = __builtin_amdgcn_mfma_f32_16x16x32_f16(ahi, bhi[j], acc[mt][j], 0, 0, 0);
        acc[mt][j] = __builtin_amdgcn_mfma_f32_16x16x32_f16(ahi, blo[j], acc[mt][j], 0, 0, 0);
        acc[mt][j] = __builtin_amdgcn_mfma_f32_16x16x32_f16(alo, bhi[j], acc[mt][j], 0, 0, 0);
      }
    }
  }
#undef ZLOAD

  // ---- S' -> LDS, split + packed (hi16 | lo16), XOR unit-swizzle ----
#pragma unroll
  for (int mt = 0; mt < 4; ++mt) {
#pragma unroll
    for (int j = 0; j < 2; ++j) {
      const int a = 32 * wv + 16 * j + l15;
#pragma unroll
      for (int r = 0; r < 4; ++r) {
        const int row = 16 * mt + 4 * h4 + r;
        const float v = acc[mt][j][r];
        const _Float16 hh = (_Float16)v;
        const _Float16 ll = (_Float16)(v - (float)hh);
        const unsigned wpk =
            ((unsigned)__builtin_bit_cast(unsigned short, hh) << 16) |
            (unsigned)__builtin_bit_cast(unsigned short, ll);
        S_lds[row * 128 + (a ^ ((row & 7) << 2))] = wpk;
      }
    }
  }
  __syncthreads();

  // ---- Stage 2 ----
  f32x4 acc2[4];
#pragma unroll
  for (int mt = 0; mt < 4; ++mt) acc2[mt] = {0.f, 0.f, 0.f, 0.f};

  const int sw = (l15 & 7) << 2;  // row&7 == l15&7 for all stage-2 rows
#pragma unroll
  for (int ks = 0; ks < 4; ++ks) {
    const int aoff = 32 * ks + 8 * h4;
    const int pc0 = aoff ^ sw;
    const int pc1 = (aoff + 4) ^ sw;
    const int foff = (16 * wv + l15) * AB + aoff;
    const half8 ahi = *(const half8*)(FYhi + foff);
    const half8 alo = *(const half8*)(FYlo + foff);

    // prefetch mt = 0
    u32x4 w0 = *(const u32x4*)&S_lds[(l15)*128 + pc0];
    u32x4 w1 = *(const u32x4*)&S_lds[(l15)*128 + pc1];
#pragma unroll
    for (int mt = 0; mt < 4; ++mt) {
      u32x4 n0, n1;
      if (mt < 3) {
        const int row2 = 16 * (mt + 1) + l15;
        n0 = *(const u32x4*)&S_lds[row2 * 128 + pc0];
        n1 = *(const u32x4*)&S_lds[row2 * 128 + pc1];
      }
      u32x4 bhu, blu;
      bhu.x = __builtin_amdgcn_perm(w0.y, w0.x, 0x07060302u);
      blu.x = __builtin_amdgcn_perm(w0.y, w0.x, 0x05040100u);
      bhu.y = __builtin_amdgcn_perm(w0.w, w0.z, 0x07060302u);
      blu.y = __builtin_amdgcn_perm(w0.w, w0.z, 0x05040100u);
      bhu.z = __builtin_amdgcn_perm(w1.y, w1.x, 0x07060302u);
      blu.z = __builtin_amdgcn_perm(w1.y, w1.x, 0x05040100u);
      bhu.w = __builtin_amdgcn_perm(w1.w, w1.z, 0x07060302u);
      blu.w = __builtin_amdgcn_perm(w1.w, w1.z, 0x05040100u);
      const half8 bh = __builtin_bit_cast(half8, bhu);
      const half8 bl = __builtin_bit_cast(half8, blu);
      acc2[mt] = __builtin_amdgcn_mfma_f32_16x16x32_f16(ahi, bh, acc2[mt], 0, 0, 0);
      acc2[mt] = __builtin_amdgcn_mfma_f32_16x16x32_f16(ahi, bl, acc2[mt], 0, 0, 0);
      acc2[mt] = __builtin_amdgcn_mfma_f32_16x16x32_f16(alo, bh, acc2[mt], 0, 0, 0);
      if (mt < 3) { w0 = n0; w1 = n1; }
    }
  }

  // ---- Epilogue: D[row = n = 16wv+4h4+r][col = m = 16mt+l15] ----
  float* __restrict__ ob = out + (size_t)img * 8192 + which * 4096;
#pragma unroll
  for (int mt = 0; mt < 4; ++mt) {
#pragma unroll
    for (int r = 0; r < 4; ++r) {
      ob[(16 * wv + 4 * h4 + r) * 64 + 16 * mt + l15] = acc2[mt][r] * gamma_eff;
    }
  }
}

extern "C" void kernel_launch(void* const* d_in, const int* in_sizes, int n_in,
                              void* d_out, int out_size, void* d_ws, size_t ws_size,
                              hipStream_t stream) {
  const float* x = (const float*)d_in[0];
  const float* xh = (const float*)d_in[1];
  const float* h = (const float*)d_in[2];
  const float* Ww = (const float*)d_in[3];
  const float* Wb = (const float*)d_in[4];
  float* outp = (float*)d_out;

  fb_setup<<<1, 1024, 0, stream>>>(h, Ww, Wb, d_ws);
  fb_filt<<<2048, 256, 0, stream>>>(x, xh, (const void*)d_ws, outp);
}

// Round 3
// 176.020 us; speedup vs baseline: 1.1117x; 1.1117x over previous
//
#include <hip/hip_runtime.h>
#include <math.h>

#define AB 128   // A == B == 128
#define NN 64    // N
#define HD 1024  // H

// fp32 -> f16 hi/lo split scales. Z ~ N(0,1) -> x256 keeps lo normal;
// F entries ~1e-2 -> x64. out = acc * gamma * 2^-20.
#define SFZ 256.0f
#define SFF 64.0f
#define DESCALE (1.0f / 1048576.0f)  // 2^-(8+6+6)

typedef _Float16 half8 __attribute__((ext_vector_type(8)));
typedef float f32x4 __attribute__((ext_vector_type(4)));
typedef unsigned u32x4 __attribute__((ext_vector_type(4)));

// ---------------------------------------------------------------------------
// ws layout (bytes):
//   [0,     32768)  FXp[m][b]  packed u32 (hi16|lo16), row-major, scaled x64
//   [32768, 49152)  FYhi[n][a] half
//   [49152, 65536)  FYlo[n][a] half
//   [65536]         float gamma * 2^-20
// ---------------------------------------------------------------------------

__device__ __forceinline__ float wave_reduce(float v) {
  v += __shfl_down(v, 32);
  v += __shfl_down(v, 16);
  v += __shfl_down(v, 8);
  v += __shfl_down(v, 4);
  v += __shfl_down(v, 2);
  v += __shfl_down(v, 1);
  return v;  // valid in lane 0
}

__global__ __launch_bounds__(1024) void fb_setup(
    const float* __restrict__ h, const float* __restrict__ Ww,
    const float* __restrict__ Wb, void* __restrict__ wsv) {
  __shared__ float redp[16][5];
  __shared__ float reds[16][2];
  __shared__ float sc[5];
  __shared__ float ssum[2];
  const int tid = threadIdx.x;
  const int lane = tid & 63;
  const int wv = tid >> 6;

  const float hv = h[tid];
  float p[5];
#pragma unroll
  for (int j = 0; j < 5; ++j) p[j] = hv * Ww[j * HD + tid];
#pragma unroll
  for (int j = 0; j < 5; ++j) {
    float r = wave_reduce(p[j]);
    if (lane == 0) redp[wv][j] = r;
  }
  __syncthreads();
  if (tid < 5) {
    float s = Wb[tid];
#pragma unroll
    for (int w = 0; w < 16; ++w) s += redp[w][tid];
    sc[tid] = s;
  }
  __syncthreads();

  const float gt_X = sc[0], gt_Y = sc[1], log_var = sc[2], log_dt = sc[3];
  const float var = expf(log_var + 1e-8f);
  const float g_X = (129.0f * (gt_X + 1.0f)) / 2.0f;
  const float g_Y = (129.0f * (gt_Y + 1.0f)) / 2.0f;
  const float d = (expf(log_dt) * 127.0f) / 63.0f;
  const float twovar = 2.0f * var;

  float fyv[8], fxv[8];
  float sY = 0.f, sX = 0.f;
#pragma unroll
  for (int c = 0; c < 8; ++c) {
    const int idx = tid + 1024 * c;
    const int n = idx >> 7;
    const int col = idx & 127;
    const float idxn = (float)n - 32.5f;
    const float muX = g_X + idxn * d;
    const float muY = g_Y + idxn * d;
    const float dx = (float)col - muX;
    const float dy = (float)col - muY;
    const float fx = expf(-(dx * dx) / twovar);
    const float fy = expf(-(dy * dy) / twovar);
    fyv[c] = fy;
    fxv[c] = fx;
    sY += fy;
    sX += fx;
  }
  {
    float rY = wave_reduce(sY);
    float rX = wave_reduce(sX);
    if (lane == 0) { reds[wv][0] = rY; reds[wv][1] = rX; }
  }
  __syncthreads();
  if (tid < 2) {
    float s = 0.f;
#pragma unroll
    for (int w = 0; w < 16; ++w) s += reds[w][tid];
    ssum[tid] = s;
  }
  __syncthreads();
  const float invY = 1.0f / ssum[0];
  const float invX = 1.0f / ssum[1];

  unsigned* FXp = (unsigned*)wsv;
  _Float16* FYhi = (_Float16*)wsv + 2 * NN * AB;  // byte 32768
  _Float16* FYlo = FYhi + NN * AB;                // byte 49152

#pragma unroll
  for (int c = 0; c < 8; ++c) {
    const int idx = tid + 1024 * c;  // == n*128 + col, row-major
    const float vy = fyv[c] * invY * SFF;
    const float vx = fxv[c] * invX * SFF;
    const _Float16 yh = (_Float16)vy;
    const _Float16 xh2 = (_Float16)vx;
    FYhi[idx] = yh;
    FYlo[idx] = (_Float16)(vy - (float)yh);
    const _Float16 xl = (_Float16)(vx - (float)xh2);
    FXp[idx] = ((unsigned)__builtin_bit_cast(unsigned short, xh2) << 16) |
               (unsigned)__builtin_bit_cast(unsigned short, xl);
  }
  if (tid == 0) ((float*)wsv)[2 * NN * AB] = expf(sc[4]) * DESCALE;
}

// ---------------------------------------------------------------------------
// fb_filt: one block (256 thr = 4 waves) per image.
// Phase 0: issue Z ks01 batch (regs); coop-copy packed FX (32 KB) into LDS
//          (XOR unit-swizzle col ^ 4*(row&7)); barrier 1.
// Stage 1: issue Z ks23 (pinned w/ sched_barrier); per ks: split Z in regs,
//          A-frags via LDS b128 + v_perm unpack, 24 MFMAs. No global loads
//          in the loop. Barrier 2 (FX reads done).
// S' -> same LDS, packed (hi16|lo16), same swizzle. FY frags (8 half8)
//          prefetched into regs. Barrier 3.
// Stage 2: per ks: LDS b128 (1-mt-ahead) + perm unpack + 12 MFMAs, FY from
//          regs. Epilogue: coalesced dword stores in out[n][m] order.
// 3-product f16 emulation: Ahi*Bhi + Ahi*Blo + Alo*Bhi (fp32 acc).
// ---------------------------------------------------------------------------
__device__ __forceinline__ void split8(const f32x4 z0, const f32x4 z1,
                                       float s, half8& hi, half8& lo) {
#pragma unroll
  for (int e = 0; e < 8; ++e) {
    const float q = (e < 4 ? z0[e] : z1[e - 4]) * s;
    const _Float16 hh = (_Float16)q;
    hi[e] = hh;
    lo[e] = (_Float16)(q - (float)hh);
  }
}

__device__ __forceinline__ void unpack8(const u32x4 a0, const u32x4 a1,
                                        half8& hi, half8& lo) {
  u32x4 hu, lu;
  hu.x = __builtin_amdgcn_perm(a0.y, a0.x, 0x07060302u);
  lu.x = __builtin_amdgcn_perm(a0.y, a0.x, 0x05040100u);
  hu.y = __builtin_amdgcn_perm(a0.w, a0.z, 0x07060302u);
  lu.y = __builtin_amdgcn_perm(a0.w, a0.z, 0x05040100u);
  hu.z = __builtin_amdgcn_perm(a1.y, a1.x, 0x07060302u);
  lu.z = __builtin_amdgcn_perm(a1.y, a1.x, 0x05040100u);
  hu.w = __builtin_amdgcn_perm(a1.w, a1.z, 0x07060302u);
  lu.w = __builtin_amdgcn_perm(a1.w, a1.z, 0x05040100u);
  hi = __builtin_bit_cast(half8, hu);
  lo = __builtin_bit_cast(half8, lu);
}

__global__ __launch_bounds__(256, 4) void fb_filt(
    const float* __restrict__ x, const float* __restrict__ xh,
    const void* __restrict__ wsv, float* __restrict__ out) {
  __shared__ __align__(16) unsigned S_lds[NN * 128];  // 32 KB: FX, then S'

  const int tid = threadIdx.x;
  const int lane = tid & 63;
  const int wv = tid >> 6;   // 0..3
  const int l15 = lane & 15;
  const int h4 = lane >> 4;  // 0..3
  const int bid = blockIdx.x;
  const int img = bid >> 1;
  const int which = bid & 1;
  const float* __restrict__ Z = (which ? xh : x) + (size_t)img * (AB * AB);
  const unsigned* __restrict__ FXp = (const unsigned*)wsv;
  const _Float16* __restrict__ FYhi = (const _Float16*)wsv + 2 * NN * AB;
  const _Float16* __restrict__ FYlo = FYhi + NN * AB;
  const float gamma_eff = ((const float*)wsv)[2 * NN * AB];

  // ---- Phase 0: Z ks01 batch + FX -> LDS coop copy ----
  const float* __restrict__ zrow = Z + (32 * wv + l15) * AB + 8 * h4;
  f32x4 z[4][4];  // [ks][j*2 + half], all indices compile-time after unroll
#pragma unroll
  for (int ks = 0; ks < 2; ++ks) {
    const float* p0 = zrow + 32 * ks;
    const float* p1 = zrow + 16 * AB + 32 * ks;
    z[ks][0] = *(const f32x4*)p0;
    z[ks][1] = *(const f32x4*)(p0 + 4);
    z[ks][2] = *(const f32x4*)p1;
    z[ks][3] = *(const f32x4*)(p1 + 4);
  }
  {
    const int swc = 4 * ((tid >> 5) & 7);  // 4*(row&7), row = c*8 + (tid>>5)
    const int colw = (tid * 4) & 127;
    const int rbase = tid >> 5;
#pragma unroll
    for (int c = 0; c < 8; ++c) {
      const u32x4 v = *(const u32x4*)(FXp + c * 1024 + tid * 4);
      *(u32x4*)&S_lds[(c * 8 + rbase) * 128 + (colw ^ swc)] = v;
    }
  }
  __syncthreads();  // barrier 1: FX table resident in LDS

  // ---- issue Z ks23, pinned so they stay ahead of stage-1 compute ----
#pragma unroll
  for (int ks = 2; ks < 4; ++ks) {
    const float* p0 = zrow + 32 * ks;
    const float* p1 = zrow + 16 * AB + 32 * ks;
    z[ks][0] = *(const f32x4*)p0;
    z[ks][1] = *(const f32x4*)(p0 + 4);
    z[ks][2] = *(const f32x4*)p1;
    z[ks][3] = *(const f32x4*)(p1 + 4);
  }
  __builtin_amdgcn_sched_barrier(0);

  // ---- Stage 1: S'(64x128) = FXs @ Zs^T ----
  f32x4 acc[4][2];  // [m-tile][a-subtile]
#pragma unroll
  for (int mt = 0; mt < 4; ++mt)
#pragma unroll
    for (int j = 0; j < 2; ++j) acc[mt][j] = {0.f, 0.f, 0.f, 0.f};

  const int sw1 = 4 * (l15 & 7);
#pragma unroll
  for (int ks = 0; ks < 4; ++ks) {
    half8 bhi[2], blo[2];
    split8(z[ks][0], z[ks][1], SFZ, bhi[0], blo[0]);
    split8(z[ks][2], z[ks][3], SFZ, bhi[1], blo[1]);
    const int c0 = (32 * ks + 8 * h4) ^ sw1;
#pragma unroll
    for (int mt = 0; mt < 4; ++mt) {
      const int base = (16 * mt + l15) * 128;
      const u32x4 a0 = *(const u32x4*)&S_lds[base + c0];
      const u32x4 a1 = *(const u32x4*)&S_lds[base + (c0 ^ 4)];
      half8 ahi, alo;
      unpack8(a0, a1, ahi, alo);
#pragma unroll
      for (int j = 0; j < 2; ++j) {
        acc[mt][j] = __builtin_amdgcn_mfma_f32_16x16x32_f16(ahi, bhi[j], acc[mt][j], 0, 0, 0);
        acc[mt][j] = __builtin_amdgcn_mfma_f32_16x16x32_f16(ahi, blo[j], acc[mt][j], 0, 0, 0);
        acc[mt][j] = __builtin_amdgcn_mfma_f32_16x16x32_f16(alo, bhi[j], acc[mt][j], 0, 0, 0);
      }
    }
  }
  __syncthreads();  // barrier 2: all FX reads complete before overwrite

  // ---- S' -> LDS, split + packed (hi16 | lo16), same XOR swizzle ----
#pragma unroll
  for (int mt = 0; mt < 4; ++mt) {
#pragma unroll
    for (int j = 0; j < 2; ++j) {
      const int a = 32 * wv + 16 * j + l15;
#pragma unroll
      for (int r = 0; r < 4; ++r) {
        const int row = 16 * mt + 4 * h4 + r;
        const float v = acc[mt][j][r];
        const _Float16 hh = (_Float16)v;
        const _Float16 ll = (_Float16)(v - (float)hh);
        const unsigned wpk =
            ((unsigned)__builtin_bit_cast(unsigned short, hh) << 16) |
            (unsigned)__builtin_bit_cast(unsigned short, ll);
        S_lds[row * 128 + ((a >> 2) * 4 ^ (4 * (row & 7))) + (a & 3)] = wpk;
      }
    }
  }

  // ---- prefetch FY frags (global) so they fly across barrier 3 ----
  half8 fyh[4], fyl[4];
#pragma unroll
  for (int ks = 0; ks < 4; ++ks) {
    const int foff = (16 * wv + l15) * AB + 32 * ks + 8 * h4;
    fyh[ks] = *(const half8*)(FYhi + foff);
    fyl[ks] = *(const half8*)(FYlo + foff);
  }
  __builtin_amdgcn_sched_barrier(0);
  __syncthreads();  // barrier 3: S' resident

  // ---- Stage 2: out(64x64) = FYs @ S'^T ----
  f32x4 acc2[4];
#pragma unroll
  for (int mt = 0; mt < 4; ++mt) acc2[mt] = {0.f, 0.f, 0.f, 0.f};

  const int sw2 = 4 * (l15 & 7);
#pragma unroll
  for (int ks = 0; ks < 4; ++ks) {
    const int c0 = (32 * ks + 8 * h4) ^ sw2;
    // prefetch mt = 0
    u32x4 w0 = *(const u32x4*)&S_lds[l15 * 128 + c0];
    u32x4 w1 = *(const u32x4*)&S_lds[l15 * 128 + (c0 ^ 4)];
#pragma unroll
    for (int mt = 0; mt < 4; ++mt) {
      u32x4 n0, n1;
      if (mt < 3) {
        const int base2 = (16 * (mt + 1) + l15) * 128;
        n0 = *(const u32x4*)&S_lds[base2 + c0];
        n1 = *(const u32x4*)&S_lds[base2 + (c0 ^ 4)];
      }
      half8 bh, bl;
      unpack8(w0, w1, bh, bl);
      acc2[mt] = __builtin_amdgcn_mfma_f32_16x16x32_f16(fyh[ks], bh, acc2[mt], 0, 0, 0);
      acc2[mt] = __builtin_amdgcn_mfma_f32_16x16x32_f16(fyh[ks], bl, acc2[mt], 0, 0, 0);
      acc2[mt] = __builtin_amdgcn_mfma_f32_16x16x32_f16(fyl[ks], bh, acc2[mt], 0, 0, 0);
      if (mt < 3) { w0 = n0; w1 = n1; }
    }
  }

  // ---- Epilogue: D[row = n = 16wv+4h4+r][col = m = 16mt+l15] ----
  float* __restrict__ ob = out + (size_t)img * 8192 + which * 4096;
#pragma unroll
  for (int mt = 0; mt < 4; ++mt) {
#pragma unroll
    for (int r = 0; r < 4; ++r) {
      ob[(16 * wv + 4 * h4 + r) * 64 + 16 * mt + l15] = acc2[mt][r] * gamma_eff;
    }
  }
}

extern "C" void kernel_launch(void* const* d_in, const int* in_sizes, int n_in,
                              void* d_out, int out_size, void* d_ws, size_t ws_size,
                              hipStream_t stream) {
  const float* x = (const float*)d_in[0];
  const float* xh = (const float*)d_in[1];
  const float* h = (const float*)d_in[2];
  const float* Ww = (const float*)d_in[3];
  const float* Wb = (const float*)d_in[4];
  float* outp = (float*)d_out;

  fb_setup<<<1, 1024, 0, stream>>>(h, Ww, Wb, d_ws);
  fb_filt<<<2048, 256, 0, stream>>>(x, xh, (const void*)d_ws, outp);
}